// Round 6
// baseline (354.007 us; speedup 1.0000x reference)
//
#include <hip/hip_runtime.h>
#include <math.h>

#define D 256
#define TBROWS 32768
#define BATCH 8

typedef __attribute__((ext_vector_type(4)))  float f32x4;
typedef __attribute__((ext_vector_type(16))) float f32x16;
typedef __attribute__((ext_vector_type(8)))  short short8v;

// ws float-offsets (total ~1.06 MB; ws re-poisoned each call -> all rewritten per launch)
#define WS_OD   0        // op_decay[256] float2          -> 512 f
#define WS_C1   512      // C1[8][256] float2 (gate*of)   -> 4096 f
#define WS_C0   4608     // C0[8][256] float2             -> 4096 f
#define WS_BHI  8704     // B'' hi frags: 262144 ushort   -> 131072 f
#define WS_BLO  139776   // B'' lo frags: 262144 ushort   -> 131072 f

__device__ __forceinline__ float sigmoidf_(float x){ return 1.0f/(1.0f+expf(-x)); }
__device__ __forceinline__ unsigned short f2bf(float f){
  unsigned int u = __float_as_uint(f);
  unsigned int r = (u + 0x7FFFu + ((u>>16)&1u)) >> 16;
  return (unsigned short)r;
}
__device__ __forceinline__ float bf2f(unsigned short h){
  return __uint_as_float(((unsigned int)h)<<16);
}

// ---- prep_batch: flux update + proj/gate + per-(b,d) epilogue coefficients ----
__global__ void prep_batch_kernel(const float* __restrict__ xg_re, const float* __restrict__ xg_im,
                                  const float* __restrict__ flux_re, const float* __restrict__ flux_im,
                                  const float* __restrict__ Wm, const float* __restrict__ bm,
                                  const float* __restrict__ decay_re, const float* __restrict__ decay_im,
                                  const float* __restrict__ Wp, const float* __restrict__ bp,
                                  const float* __restrict__ Wg, const float* __restrict__ bg,
                                  const float* __restrict__ lam_re, const float* __restrict__ lam_im,
                                  const int* __restrict__ dt_p,
                                  float* __restrict__ ws, float* __restrict__ out_flux, int cplx){
  __shared__ float vin[512];
  __shared__ float mid[768];
  const int b = blockIdx.x, j = threadIdx.x;
  if (j < 512) vin[j] = (j < D) ? xg_re[b*D + j] : xg_im[b*D + (j - D)];
  __syncthreads();
  if (j < 512){
    const float4* row4 = (const float4*)(Wm + j*512);
    const float4* x4p  = (const float4*)vin;
    float acc = 0.f;
    #pragma unroll 8
    for (int k = 0; k < 128; ++k){
      float4 w4 = row4[k]; float4 x4 = x4p[k];
      acc += w4.x*x4.x + w4.y*x4.y + w4.z*x4.z + w4.w*x4.w;
    }
    mid[j] = acc + bm[j];
  }
  __syncthreads();
  if (j < D){
    float ur = mid[j], ui = mid[D + j];
    float fdr = sigmoidf_(decay_re[j]);
    float fdi = decay_im[j];
    float fr = flux_re[b*D + j], fi = flux_im[b*D + j];
    float nr = fr*fdr - fi*fdi + ur;
    float ni = fr*fdi + fi*fdr + ui;
    vin[j]     = nr;
    vin[D + j] = ni;
    if (cplx){ out_flux[(b*D + j)*2] = nr; out_flux[(b*D + j)*2 + 1] = ni; }
    else     { out_flux[b*D + j] = nr; }
  }
  __syncthreads();
  {
    const float* rowp = (j < 512) ? (Wp + j*512) : (Wg + (j - 512)*512);
    float bias = (j < 512) ? bp[j] : bg[j - 512];
    const float4* row4 = (const float4*)rowp;
    const float4* x4p  = (const float4*)vin;
    float acc = 0.f;
    #pragma unroll 8
    for (int k = 0; k < 128; ++k){
      float4 w4 = row4[k]; float4 x4 = x4p[k];
      acc += w4.x*x4.x + w4.y*x4.y + w4.z*x4.z + w4.w*x4.w;
    }
    mid[j] = acc + bias;
  }
  __syncthreads();
  if (j < D){
    float sr = mid[j], si = mid[D + j];
    float g = sigmoidf_(mid[512 + j]);
    g = fminf(fmaxf(g, 0.01f), 0.99f);
    float lrb = fminf(fmaxf(lam_re[j], -0.3f), 0.3f);
    float li  = lam_im[j];
    float dtr = (float)dt_p[0];
    float er  = expf(lrb * dtr);
    float ang = li * dtr;
    float odr = er * cosf(ang), odi = er * sinf(ang);
    float sarg = lrb + 1e-12f;
    float sgn = (sarg > 0.f) ? 1.f : ((sarg < 0.f) ? -1.f : 0.f);
    float lrs = lrb + 1e-8f * sgn;
    float nr = odr - 1.f, ni = odi;
    float den = lrs*lrs + li*li;
    float ofr = (nr*lrs + ni*li) / den;
    float ofi = (ni*lrs - nr*li) / den;
    ws[WS_C1 + (b*D + j)*2]     = g * ofr;
    ws[WS_C1 + (b*D + j)*2 + 1] = g * ofi;
    float s1r = sr*(1.f - g), s1i = si*(1.f - g);
    ws[WS_C0 + (b*D + j)*2]     = s1r*ofr - s1i*ofi;
    ws[WS_C0 + (b*D + j)*2 + 1] = s1r*ofi + s1i*ofr;
    if (b == 0){
      ws[WS_OD + j*2]     = odr;
      ws[WS_OD + j*2 + 1] = odi;
    }
  }
}

// ---- prep_B: B''[512][512] (hi/lo bf16) in MFMA fragment order (verified r5) ----
__global__ void prep_B_kernel(const float* __restrict__ U_re, const float* __restrict__ U_im,
                              const float* __restrict__ dft_w, float* __restrict__ ws){
  const int kp = blockIdx.x;     // k' 0..511
  const int jj = threadIdx.x;    // 0..511
  const int k  = kp & 255, half = kp >> 8;
  const int j  = jj >> 1,  part = jj & 1;
  float w = sigmoidf_(dft_w[0]);
  const float c = -6.283185307179586f;
  float t1 = c * (float)j;
  float ph = (t1 * (float)k) / 256.0f;
  float dre = cosf(ph) * 0.0625f;
  float dim = sinf(ph) * 0.0625f;
  float mr = (1.f - w)*U_re[k*D + j] + w*dre;
  float mi = (1.f - w)*U_im[k*D + j] + w*dim;
  float V = part ? (half ? mr : mi) : (half ? -mi : mr);
  unsigned short hi = f2bf(V);
  unsigned short lo = f2bf(V - bf2f(hi));
  int s = kp >> 4, rb = kp & 15;
  int hi5 = rb >> 3, j8 = rb & 7;
  int ct = jj >> 5, lane = hi5*32 + (jj & 31);
  size_t off = ((size_t)(s*16 + ct)*64 + lane)*8 + j8;
  ((unsigned short*)(ws + WS_BHI))[off] = hi;
  ((unsigned short*)(ws + WS_BLO))[off] = lo;
}

// ---- main v2: 2048 blocks x 256 thr (4 waves). Block = 64 rows x 128 jj.
// Wave w -> col-tile CT = cb*4+w. 2 row-tiles/wave. Double-buffered LDS staging
// with register prefetch (issue next chunk's loads before compute). XCD swizzle.
__global__ __launch_bounds__(256, 4) void main_mfma_kernel(
    const float* __restrict__ x_re, const float* __restrict__ x_im,
    const float* __restrict__ h_re, const float* __restrict__ h_im,
    const float* __restrict__ ws, float* __restrict__ out, int cplx){
  __shared__ short Ah[2][2048];   // [buf][(g*64+lane)*8+j8], g = sl*2+rt
  __shared__ short Al[2][2048];
  const int tid  = threadIdx.x;
  const int lane = tid & 63;
  const int wv   = tid >> 6;            // 0..3
  // XCD-aware swizzle: 2048 blocks = 8 XCDs x 256; col-siblings co-XCD
  const int bid  = blockIdx.x;
  const int swz  = (bid & 7)*256 + (bid >> 3);
  const int cb   = swz & 3;             // col-block: jj0 = cb*128
  const int row0 = (swz >> 2) * 64;
  const int b    = row0 >> 12;
  const int CT   = cb*4 + wv;           // global col-tile 0..15
  const unsigned short* Bh0 = (const unsigned short*)(ws + WS_BHI);
  const unsigned short* Bl0 = (const unsigned short*)(ws + WS_BLO);

  f32x16 acc0 = {}; f32x16 acc1 = {};

  // staging map: thread -> (row, 8 consecutive k) = one j8-octet
  const int srow = tid >> 2;            // 0..63
  const int kb   = (tid & 3) * 8;       // 0,8,16,24
  const int soff = (((kb>>4)*2 + (srow>>5))*64 + ((kb>>3)&1)*32 + (srow&31))*8;

  f32x4 p0, p1;
  auto loadx = [&](int c){
    const float* src = (c < 8) ? x_re : x_im;
    const float* base = src + (size_t)(row0 + srow)*256 + (c & 7)*32 + kb;
    p0 = *(const f32x4*)base;
    p1 = *(const f32x4*)(base + 4);
  };
  auto cvt_write = [&](int buf){
    short8v hv, lv;
    #pragma unroll
    for (int q = 0; q < 4; ++q){
      float f = p0[q];
      unsigned short hb = f2bf(f);
      hv[q] = (short)hb; lv[q] = (short)f2bf(f - bf2f(hb));
    }
    #pragma unroll
    for (int q = 0; q < 4; ++q){
      float f = p1[q];
      unsigned short hb = f2bf(f);
      hv[4+q] = (short)hb; lv[4+q] = (short)f2bf(f - bf2f(hb));
    }
    *(short8v*)&Ah[buf][soff] = hv;
    *(short8v*)&Al[buf][soff] = lv;
  };

  loadx(0);
  cvt_write(0);
  int cur = 0;
  for (int c = 0; c < 16; ++c){
    __syncthreads();                    // buf[cur] ready; prior reads of buf[cur^1] done
    if (c < 15) loadx(c + 1);           // issue next global loads early
    #pragma unroll
    for (int sl = 0; sl < 2; ++sl){
      const int g = sl*2;
      const size_t boff = ((size_t)((c*2 + sl)*16 + CT)*64 + lane)*8;
      short8v bh = *(const short8v*)(Bh0 + boff);
      short8v bl = *(const short8v*)(Bl0 + boff);
      short8v ah0 = *(const short8v*)&Ah[cur][((g+0)*64 + lane)*8];
      short8v al0 = *(const short8v*)&Al[cur][((g+0)*64 + lane)*8];
      short8v ah1 = *(const short8v*)&Ah[cur][((g+1)*64 + lane)*8];
      short8v al1 = *(const short8v*)&Al[cur][((g+1)*64 + lane)*8];
      acc0 = __builtin_amdgcn_mfma_f32_32x32x16_bf16(ah0, bh, acc0, 0,0,0);
      acc1 = __builtin_amdgcn_mfma_f32_32x32x16_bf16(ah1, bh, acc1, 0,0,0);
      acc0 = __builtin_amdgcn_mfma_f32_32x32x16_bf16(al0, bh, acc0, 0,0,0);
      acc1 = __builtin_amdgcn_mfma_f32_32x32x16_bf16(al1, bh, acc1, 0,0,0);
      acc0 = __builtin_amdgcn_mfma_f32_32x32x16_bf16(ah0, bl, acc0, 0,0,0);
      acc1 = __builtin_amdgcn_mfma_f32_32x32x16_bf16(ah1, bl, acc1, 0,0,0);
    }
    if (c < 15) cvt_write(cur ^ 1);     // implicit vmcnt wait on p0/p1 here
    cur ^= 1;
  }

  // epilogue: lane-pair (re,im) combine + h update
  const int j = cb*64 + wv*16 + ((lane & 31) >> 1);
  const int part = lane & 1;
  const float odr = ws[WS_OD + j*2],           odi = ws[WS_OD + j*2 + 1];
  const float c1r = ws[WS_C1 + (b*D + j)*2],   c1i = ws[WS_C1 + (b*D + j)*2 + 1];
  const float c0r = ws[WS_C0 + (b*D + j)*2],   c0i = ws[WS_C0 + (b*D + j)*2 + 1];
  #pragma unroll
  for (int rt = 0; rt < 2; ++rt){
    #pragma unroll
    for (int r = 0; r < 16; ++r){
      float val = (rt == 0) ? acc0[r] : acc1[r];
      float other = __shfl_xor(val, 1);
      float xr = part ? other : val;
      float xi = part ? val   : other;
      int row = row0 + rt*32 + 4*(lane>>5) + (r & 3) + 8*(r >> 2);
      float hr = h_re[(size_t)row*256 + j];
      float hi = h_im[(size_t)row*256 + j];
      float ore = hr*odr - hi*odi + xr*c1r - xi*c1i + c0r;
      float oim = hr*odi + hi*odr + xr*c1i + xi*c1r + c0i;
      if (cplx){
        out[((size_t)row*256 + j)*2 + part] = part ? oim : ore;
      } else if (!part){
        out[(size_t)row*256 + j] = ore;
      }
    }
  }
}

extern "C" void kernel_launch(void* const* d_in, const int* in_sizes, int n_in,
                              void* d_out, int out_size, void* d_ws, size_t ws_size,
                              hipStream_t stream){
  const float* h_re    = (const float*)d_in[0];
  const float* h_im    = (const float*)d_in[1];
  const float* x_re    = (const float*)d_in[2];
  const float* x_im    = (const float*)d_in[3];
  const float* xg_re   = (const float*)d_in[4];
  const float* xg_im   = (const float*)d_in[5];
  const float* flux_re = (const float*)d_in[6];
  const float* flux_im = (const float*)d_in[7];
  const float* U_re    = (const float*)d_in[8];
  const float* U_im    = (const float*)d_in[9];
  const float* dft_w   = (const float*)d_in[10];
  const float* decay_re= (const float*)d_in[11];
  const float* decay_im= (const float*)d_in[12];
  const float* Wm      = (const float*)d_in[13];
  const float* bm      = (const float*)d_in[14];
  const float* Wp      = (const float*)d_in[15];
  const float* bp      = (const float*)d_in[16];
  const float* Wg      = (const float*)d_in[17];
  const float* bg      = (const float*)d_in[18];
  const float* lam_re  = (const float*)d_in[19];
  const float* lam_im  = (const float*)d_in[20];
  const int*   dt      = (const int*)d_in[21];
  float* ws  = (float*)d_ws;
  float* out = (float*)d_out;

  const int cplx = (out_size >= 2*TBROWS*D) ? 1 : 0;
  float* out_flux = out + (size_t)TBROWS*D*(cplx ? 2 : 1);

  prep_batch_kernel<<<BATCH, 768, 0, stream>>>(xg_re, xg_im, flux_re, flux_im, Wm, bm,
                                               decay_re, decay_im, Wp, bp, Wg, bg,
                                               lam_re, lam_im, dt, ws, out_flux, cplx);
  prep_B_kernel<<<512, 512, 0, stream>>>(U_re, U_im, dft_w, ws);
  main_mfma_kernel<<<2048, 256, 0, stream>>>(x_re, x_im, h_re, h_im, ws, out, cplx);
}